// Round 9
// baseline (239.653 us; speedup 1.0000x reference)
//
#include <hip/hip_runtime.h>
#include <hip/hip_bf16.h>
#include <math.h>

#define NN 100000
#define DIM 128
#define EPSF 1e-4f
#define LN_EPSF 1e-5f
#define XSTR 136          // padded ushort stride: 272 B rows (16B-aligned, 2-way banks max)
#define NTILES 3125       // 32-row tiles
#define TPB 4             // tiles per block -> grid 782 <= 1024 resident (4 blk/CU cap)
#define GEMM_GRID ((NTILES + TPB - 1) / TPB)   // 782
#define CAP 32            // bucket row = 128 B; Poisson(8): P(row>=32) ~ 1e-10

typedef float  floatx4 __attribute__((ext_vector_type(4)));
typedef short  shortx8 __attribute__((ext_vector_type(8)));

__device__ __forceinline__ ushort f2b(float f) {
    union { float f; unsigned u; } c; c.f = f;
    unsigned lsb = (c.u >> 16) & 1u;
    return (ushort)((c.u + 0x7fffu + lsb) >> 16);   // RNE
}
__device__ __forceinline__ float b2f(ushort b) {
    union { unsigned u; float f; } c; c.u = ((unsigned)b) << 16;
    return c.f;
}
__device__ __forceinline__ unsigned pk2(float a, float b) {
    union { __hip_bfloat162 h2; unsigned u; } c;
    c.h2 = __float22bfloat162_rn(float2{a, b});     // v_cvt_pk_bf16_f32
    return c.u;
}

// ---------------------------------------------------------------------------
// MFMA triple GEMM (swapped operands: D[m=col][n=node]) + FUSED bucket fill.
// W fragments loaded directly from fp32 weights per block (pack kernel
// eliminated; ~192 L2-hit dword loads once per block, amortized over TPB=4
// tiles). Fill is pure mem-latency work hidden under the MFMA pipeline.
// ---------------------------------------------------------------------------
__global__ __launch_bounds__(256) void gemm3_mfma_kernel(
    const float* __restrict__ x,
    const float* __restrict__ Wfc, const float* __restrict__ Wrate,
    const float* __restrict__ Wrob,
    const float* __restrict__ bfc, const float* __restrict__ brob,
    ushort* __restrict__ h, ushort* __restrict__ rate, ushort* __restrict__ gam,
    const int* __restrict__ ei, int* __restrict__ cur,
    int* __restrict__ bucket, int E)
{
    __shared__ ushort xs[32 * XSTR];            // 8704 B
    __shared__ ushort outb[3 * 32 * XSTR];      // 26112 B
    const int tid  = threadIdx.x;
    const int wv   = tid >> 6;
    const int lane = tid & 63;

    // ---- fused edge->bucket fill: grid-stride (4 iterations at grid 782)
    for (int e = blockIdx.x * 256 + tid; e < E; e += GEMM_GRID * 256) {
        const int row = ei[e];
        const int col = ei[E + e];
        const int pos = atomicAdd(&cur[row], 1);
        if (pos < CAP) bucket[(size_t)row * CAP + pos] = col;
    }

    // ---- W fragments (A operand; 24 per wave) loaded directly from fp32 W.
    // lane holds W[k=ks*32+(lane>>4)*8+j][n=nt*16+(lane&15)], same mapping the
    // old pack kernel produced.
    const float* Ws[3] = {Wfc, Wrate, Wrob};
    shortx8 bfrag[3][2][4];
#pragma unroll
    for (int w = 0; w < 3; ++w)
#pragma unroll
        for (int t = 0; t < 2; ++t) {
            const int n = (wv * 2 + t) * 16 + (lane & 15);
#pragma unroll
            for (int ks = 0; ks < 4; ++ks) {
                const int kb = ks * 32 + (lane >> 4) * 8;
                union { shortx8 v; ushort u[8]; } tmp;
#pragma unroll
                for (int j = 0; j < 8; ++j)
                    tmp.u[j] = f2b(Ws[w][(size_t)(kb + j) * DIM + n]);
                bfrag[w][t][ks] = tmp.v;
            }
        }

    // ---- per-lane bias: 4 consecutive cols per t
    float4 bias_fc[2], bias_rob[2];
#pragma unroll
    for (int t = 0; t < 2; ++t) {
        const int colbase = wv * 32 + t * 16 + (lane >> 4) * 4;
        bias_fc[t]  = ((const float4*)bfc)[colbase >> 2];
        bias_rob[t] = ((const float4*)brob)[colbase >> 2];
    }

    const int tile0  = blockIdx.x * TPB;
    const int ntiles = (NTILES - tile0 < TPB) ? (NTILES - tile0) : TPB;

    // ---- stage tile 0
    {
        const size_t row0 = (size_t)tile0 * 32;
#pragma unroll
        for (int k = 0; k < 4; ++k) {
            const int i = tid + k * 256, r = i >> 5, c4 = i & 31;
            const float4 v = ((const float4*)(x + (row0 + r) * DIM))[c4];
            uint2 uu; uu.x = pk2(v.x, v.y); uu.y = pk2(v.z, v.w);
            *(uint2*)&xs[r * XSTR + c4 * 4] = uu;
        }
    }
    __syncthreads();

    for (int ti = 0; ti < ntiles; ++ti) {
        const size_t row0 = (size_t)(tile0 + ti) * 32;
        const bool hasnext = (ti + 1 < ntiles);

        // prefetch next x tile into regs (hides HBM latency under MFMA)
        float4 pf[4];
        if (hasnext) {
            const size_t nrow0 = row0 + 32;
#pragma unroll
            for (int k = 0; k < 4; ++k) {
                const int i = tid + k * 256, r = i >> 5, c4 = i & 31;
                pf[k] = ((const float4*)(x + (nrow0 + r) * DIM))[c4];
            }
        }

        // ---- two 16-node sub-tiles: MFMA then epilogue into LDS
#pragma unroll
        for (int rt = 0; rt < 2; ++rt) {
            shortx8 af[4];
#pragma unroll
            for (int ks = 0; ks < 4; ++ks)
                af[ks] = *(const shortx8*)&xs[(rt * 16 + (lane & 15)) * XSTR
                                              + ks * 32 + (lane >> 4) * 8];
            floatx4 acc[3][2] = {};
#pragma unroll
            for (int ks = 0; ks < 4; ++ks)
#pragma unroll
                for (int w = 0; w < 3; ++w)
#pragma unroll
                    for (int t = 0; t < 2; ++t)
                        acc[w][t] = __builtin_amdgcn_mfma_f32_16x16x32_bf16(
                            bfrag[w][t][ks], af[ks], acc[w][t], 0, 0, 0);

            const int node = rt * 16 + (lane & 15);
#pragma unroll
            for (int t = 0; t < 2; ++t) {
                const int colbase = wv * 32 + t * 16 + (lane >> 4) * 4;
                {   // h = acc0 + bfc
                    uint2 st;
                    st.x = pk2(acc[0][t][0] + bias_fc[t].x, acc[0][t][1] + bias_fc[t].y);
                    st.y = pk2(acc[0][t][2] + bias_fc[t].z, acc[0][t][3] + bias_fc[t].w);
                    *(uint2*)&outb[0 * 32 * XSTR + node * XSTR + colbase] = st;
                }
                {   // rate = softplus(acc1) + eps
                    float rv[4];
#pragma unroll
                    for (int r = 0; r < 4; ++r) {
                        const float v = acc[1][t][r];
                        rv[r] = fmaxf(v, 0.f) + __logf(1.f + __expf(-fabsf(v))) + EPSF;
                    }
                    uint2 st; st.x = pk2(rv[0], rv[1]); st.y = pk2(rv[2], rv[3]);
                    *(uint2*)&outb[1 * 32 * XSTR + node * XSTR + colbase] = st;
                }
                {   // gam = acc2 + brob
                    uint2 st;
                    st.x = pk2(acc[2][t][0] + bias_rob[t].x, acc[2][t][1] + bias_rob[t].y);
                    st.y = pk2(acc[2][t][2] + bias_rob[t].z, acc[2][t][3] + bias_rob[t].w);
                    *(uint2*)&outb[2 * 32 * XSTR + node * XSTR + colbase] = st;
                }
            }
        }
        __syncthreads();   // outb ready; xs reads done

        // ---- coalesced stores: wave writes 1KB contiguous runs
#pragma unroll
        for (int k = 0; k < 6; ++k) {
            const int w = k >> 1;
            const int rem = tid + (k & 1) * 256;        // 0..511
            const int node = rem >> 4, seg = rem & 15;  // seg: 16B chunk in row
            const uint4 v = *(const uint4*)&outb[w * 32 * XSTR + node * XSTR + seg * 8];
            ushort* dstw = (w == 0) ? h : (w == 1) ? rate : gam;
            *(uint4*)(dstw + (row0 + node) * DIM + seg * 8) = v;
        }

        // ---- stage prefetched next tile into xs
        if (hasnext) {
#pragma unroll
            for (int k = 0; k < 4; ++k) {
                const int i = tid + k * 256, r = i >> 5, c4 = i & 31;
                uint2 uu; uu.x = pk2(pf[k].x, pf[k].y); uu.y = pk2(pf[k].z, pf[k].w);
                *(uint2*)&xs[r * XSTR + c4 * 4] = uu;
            }
        }
        __syncthreads();   // xs ready; outb free
    }
}

// ---------------------------------------------------------------------------
// Fused gather + finalize + LayerNorm. One wave per FOUR rows; bucket rows
// loaded coalesced up-front, cols broadcast via shfl; gathers issued in
// fully-predicated 4x4 batches (16 independent loads in flight, no serial
// per-row tail loops). OOB slots clamp to row 0 and are masked in the add.
// ---------------------------------------------------------------------------
__global__ __launch_bounds__(256) void finalize_kernel(
    const ushort* __restrict__ h, const ushort* __restrict__ rate,
    const ushort* __restrict__ gam,
    const int* __restrict__ cur, const int* __restrict__ bucket,
    const int* __restrict__ degree,
    const float* __restrict__ ln_g, const float* __restrict__ ln_b,
    float* __restrict__ out)
{
    const int wave = threadIdx.x >> 6;
    const int lane = threadIdx.x & 63;
    const size_t r0 = (size_t)blockIdx.x * 16 + wave * 4;
    const unsigned* hu = (const unsigned*)h;

    // independent up-front loads (no chains)
    int nR[4]; float dgR[4]; int bvR[4];
    unsigned hvR[4], rvR[4], gvR[4];
#pragma unroll
    for (int q = 0; q < 4; ++q) {
        const size_t r = r0 + q;
        nR[q]  = cur[r];
        dgR[q] = (float)degree[r];
        bvR[q] = bucket[r * CAP + (lane & 31)];   // valid for idx < nR[q]
        hvR[q] = hu[r * 64 + lane];
        rvR[q] = ((const unsigned*)rate)[r * 64 + lane];
        gvR[q] = ((const unsigned*)gam)[r * 64 + lane];
    }
    const float2 lg = ((const float2*)ln_g)[lane];
    const float2 lb = ((const float2*)ln_b)[lane];

    float ax[4] = {0.f, 0.f, 0.f, 0.f}, ay[4] = {0.f, 0.f, 0.f, 0.f};
    const int mx = max(max(nR[0], nR[1]), max(nR[2], nR[3]));   // wave-uniform

    for (int j = 0; j < mx; j += 4) {
        unsigned v[4][4];
#pragma unroll
        for (int q = 0; q < 4; ++q)
#pragma unroll
            for (int p = 0; p < 4; ++p) {
                const int c = (j + p < nR[q]) ? __shfl(bvR[q], j + p, 64) : 0;
                v[q][p] = hu[(size_t)c * 64 + lane];
            }
#pragma unroll
        for (int q = 0; q < 4; ++q)
#pragma unroll
            for (int p = 0; p < 4; ++p) {
                const bool ok = (j + p < nR[q]);
                ax[q] += ok ? b2f((ushort)(v[q][p] & 0xffff)) : 0.f;
                ay[q] += ok ? b2f((ushort)(v[q][p] >> 16))    : 0.f;
            }
    }

    // ---- per-row math + LN + store
#pragma unroll
    for (int q = 0; q < 4; ++q) {
        const size_t row = r0 + q;
        const float cn = (float)nR[q];
        const float dg = dgR[q];

        const float h0 = b2f((ushort)(hvR[q] & 0xffff)), h1 = b2f((ushort)(hvR[q] >> 16));
        const float r0f = b2f((ushort)(rvR[q] & 0xffff)), r1f = b2f((ushort)(rvR[q] >> 16));
        const float g0 = b2f((ushort)(gvR[q] & 0xffff)), g1 = b2f((ushort)(gvR[q] >> 16));

        const float a0 = cn * h0 + ax[q];
        const float a1 = cn * h1 + ay[q];
        const float y0 = (r0f * a0 + g0) / (1.f + r0f * dg + EPSF);
        const float y1 = (r1f * a1 + g1) / (1.f + r1f * dg + EPSF);

        float s  = y0 + y1;
        float s2 = y0 * y0 + y1 * y1;
#pragma unroll
        for (int o = 32; o > 0; o >>= 1) {
            s  += __shfl_xor(s,  o, 64);
            s2 += __shfl_xor(s2, o, 64);
        }
        const float mean = s * (1.f / 128.f);
        const float var  = s2 * (1.f / 128.f) - mean * mean;
        const float inv  = rsqrtf(var + LN_EPSF);

        float2 o;
        o.x = (y0 - mean) * inv * lg.x + lb.x;
        o.y = (y1 - mean) * inv * lg.y + lb.y;
        ((float2*)(out + row * DIM))[lane] = o;
    }
}

// ---------------------------------------------------------------------------
extern "C" void kernel_launch(void* const* d_in, const int* in_sizes, int n_in,
                              void* d_out, int out_size, void* d_ws, size_t ws_size,
                              hipStream_t stream)
{
    const float* x      = (const float*)d_in[0];
    const int*   ei     = (const int*)  d_in[1];
    const int*   degree = (const int*)  d_in[2];
    const float* Wfc    = (const float*)d_in[3];
    const float* bfc    = (const float*)d_in[4];
    const float* Wrate  = (const float*)d_in[5];
    const float* Wrob   = (const float*)d_in[6];
    const float* brob   = (const float*)d_in[7];
    const float* ln_g   = (const float*)d_in[8];
    const float* ln_b   = (const float*)d_in[9];
    float* out = (float*)d_out;

    const int E = in_sizes[1] / 2;   // 800000
    const size_t NEL = (size_t)NN * DIM;

    ushort* h     = (ushort*)d_ws;
    ushort* rate  = h + NEL;
    ushort* gam   = rate + NEL;
    int*   cur    = (int*)(gam + NEL);
    int*   bucket = cur + NN;             // NN*CAP ints = 12.8 MB

    hipMemsetAsync(cur, 0, NN * sizeof(int), stream);
    gemm3_mfma_kernel<<<GEMM_GRID, 256, 0, stream>>>(x, Wfc, Wrate, Wrob,
                                                     bfc, brob, h, rate, gam,
                                                     ei, cur, bucket, E);
    finalize_kernel<<<NN / 16, 256, 0, stream>>>(h, rate, gam, cur, bucket,
                                                 degree, ln_g, ln_b, out);
}

// Round 10
// 217.995 us; speedup vs baseline: 1.0994x; 1.0994x over previous
//
#include <hip/hip_runtime.h>
#include <hip/hip_bf16.h>
#include <math.h>

#define NN 100000
#define DIM 128
#define EPSF 1e-4f
#define LN_EPSF 1e-5f
#define XSTR 136          // padded ushort stride: 272 B rows (16B-aligned, 2-way banks max)
#define NTILES 3125       // 32-row tiles
#define TPB 2             // tiles per block -> grid 1563 (TPB=4 measured WORSE: r9 102us vs r8 78us)
#define GEMM_GRID ((NTILES + TPB - 1) / TPB)   // 1563
#define PACK_GRID ((NN + 255) / 256)
#define CAP 32            // bucket row = 128 B; Poisson(8): P(row>=32) ~ 1e-10

typedef float  floatx4 __attribute__((ext_vector_type(4)));
typedef short  shortx8 __attribute__((ext_vector_type(8)));

__device__ __forceinline__ ushort f2b(float f) {
    union { float f; unsigned u; } c; c.f = f;
    unsigned lsb = (c.u >> 16) & 1u;
    return (ushort)((c.u + 0x7fffu + lsb) >> 16);   // RNE
}
__device__ __forceinline__ float b2f(ushort b) {
    union { unsigned u; float f; } c; c.u = ((unsigned)b) << 16;
    return c.f;
}
__device__ __forceinline__ unsigned pk2(float a, float b) {
    union { __hip_bfloat162 h2; unsigned u; } c;
    c.h2 = __float22bfloat162_rn(float2{a, b});     // v_cvt_pk_bf16_f32
    return c.u;
}

// ---------------------------------------------------------------------------
// pack weights into MFMA fragment layout + zero cur[] (no memset dispatch).
// Bpack[w][nt(8)][ks(4)][lane(64)][j(8)]: lane holds
// W[k=ks*32+(lane>>4)*8+j][n=nt*16+(lane&15)].
// (r9 measured: loading W fragments in-gemm from fp32 costs ~96 strided
//  scalar loads/thread at each block's start -> keep the pack kernel.)
// ---------------------------------------------------------------------------
__global__ __launch_bounds__(256) void pack_kernel(
    const float* __restrict__ Wfc, const float* __restrict__ Wrate,
    const float* __restrict__ Wrob, ushort* __restrict__ Bpack,
    int* __restrict__ cur)
{
    const int id = blockIdx.x * 256 + threadIdx.x;
    if (id < NN) cur[id] = 0;
    if (id >= 6144) return;                          // 3*8*4*64
    const int lane = id & 63;
    const int ks   = (id >> 6) & 3;
    const int nt   = (id >> 8) & 7;
    const int w    = id >> 11;
    const float* W = (w == 0) ? Wfc : (w == 1) ? Wrate : Wrob;
    const int n  = nt * 16 + (lane & 15);
    const int kb = ks * 32 + (lane >> 4) * 8;
    ushort tmp[8];
#pragma unroll
    for (int j = 0; j < 8; ++j) tmp[j] = f2b(W[(kb + j) * DIM + n]);
    ushort* dst = Bpack + (size_t)id * 8;
#pragma unroll
    for (int j = 0; j < 8; ++j) dst[j] = tmp[j];
}

// ---------------------------------------------------------------------------
// MFMA triple GEMM (swapped operands: D[m=col][n=node]) + FUSED bucket fill.
// Fill is pure mem-latency work (atomic pos + scattered 4B store), hidden
// under the MFMA pipeline (r7: standalone fill = 60us at 0.4% VALUBusy;
// fused it costs ~+19us on the gemm -> net win).
// ---------------------------------------------------------------------------
__global__ __launch_bounds__(256) void gemm3_mfma_kernel(
    const float* __restrict__ x,
    const ushort* __restrict__ Bpack,
    const float* __restrict__ bfc, const float* __restrict__ brob,
    ushort* __restrict__ h, ushort* __restrict__ rate, ushort* __restrict__ gam,
    const int* __restrict__ ei, int* __restrict__ cur,
    int* __restrict__ bucket, int E)
{
    __shared__ ushort xs[32 * XSTR];            // 8704 B
    __shared__ ushort outb[3 * 32 * XSTR];      // 26112 B
    const int tid  = threadIdx.x;
    const int wv   = tid >> 6;
    const int lane = tid & 63;

    // ---- fused edge->bucket fill: 2 edges per thread, grid covers E
    {
        const int e = blockIdx.x * 512 + tid;
#pragma unroll
        for (int q = 0; q < 2; ++q) {
            const int ee = e + q * 256;
            if (ee < E) {
                const int row = ei[ee];
                const int col = ei[E + ee];
                const int pos = atomicAdd(&cur[row], 1);
                if (pos < CAP) bucket[(size_t)row * CAP + pos] = col;
            }
        }
    }

    // ---- W fragments (A operand; 24 per wave) into registers
    shortx8 bfrag[3][2][4];
#pragma unroll
    for (int w = 0; w < 3; ++w)
#pragma unroll
        for (int t = 0; t < 2; ++t) {
            const int nt = wv * 2 + t;
#pragma unroll
            for (int ks = 0; ks < 4; ++ks) {
                const ushort* p = Bpack + ((((size_t)w * 8 + nt) * 4 + ks) * 64 + lane) * 8;
                bfrag[w][t][ks] = *(const shortx8*)p;
            }
        }

    // ---- per-lane bias: 4 consecutive cols per t
    float4 bias_fc[2], bias_rob[2];
#pragma unroll
    for (int t = 0; t < 2; ++t) {
        const int colbase = wv * 32 + t * 16 + (lane >> 4) * 4;
        bias_fc[t]  = ((const float4*)bfc)[colbase >> 2];
        bias_rob[t] = ((const float4*)brob)[colbase >> 2];
    }

    const int tile0  = blockIdx.x * TPB;
    const int ntiles = (NTILES - tile0 < TPB) ? (NTILES - tile0) : TPB;

    // ---- stage tile 0
    {
        const size_t row0 = (size_t)tile0 * 32;
#pragma unroll
        for (int k = 0; k < 4; ++k) {
            const int i = tid + k * 256, r = i >> 5, c4 = i & 31;
            const float4 v = ((const float4*)(x + (row0 + r) * DIM))[c4];
            uint2 uu; uu.x = pk2(v.x, v.y); uu.y = pk2(v.z, v.w);
            *(uint2*)&xs[r * XSTR + c4 * 4] = uu;
        }
    }
    __syncthreads();

    for (int ti = 0; ti < ntiles; ++ti) {
        const size_t row0 = (size_t)(tile0 + ti) * 32;
        const bool hasnext = (ti + 1 < ntiles);

        // prefetch next x tile into regs (hides HBM latency under MFMA)
        float4 pf[4];
        if (hasnext) {
            const size_t nrow0 = row0 + 32;
#pragma unroll
            for (int k = 0; k < 4; ++k) {
                const int i = tid + k * 256, r = i >> 5, c4 = i & 31;
                pf[k] = ((const float4*)(x + (nrow0 + r) * DIM))[c4];
            }
        }

        // ---- two 16-node sub-tiles: MFMA then epilogue into LDS
#pragma unroll
        for (int rt = 0; rt < 2; ++rt) {
            shortx8 af[4];
#pragma unroll
            for (int ks = 0; ks < 4; ++ks)
                af[ks] = *(const shortx8*)&xs[(rt * 16 + (lane & 15)) * XSTR
                                              + ks * 32 + (lane >> 4) * 8];
            floatx4 acc[3][2] = {};
#pragma unroll
            for (int ks = 0; ks < 4; ++ks)
#pragma unroll
                for (int w = 0; w < 3; ++w)
#pragma unroll
                    for (int t = 0; t < 2; ++t)
                        acc[w][t] = __builtin_amdgcn_mfma_f32_16x16x32_bf16(
                            bfrag[w][t][ks], af[ks], acc[w][t], 0, 0, 0);

            const int node = rt * 16 + (lane & 15);
#pragma unroll
            for (int t = 0; t < 2; ++t) {
                const int colbase = wv * 32 + t * 16 + (lane >> 4) * 4;
                {   // h = acc0 + bfc
                    uint2 st;
                    st.x = pk2(acc[0][t][0] + bias_fc[t].x, acc[0][t][1] + bias_fc[t].y);
                    st.y = pk2(acc[0][t][2] + bias_fc[t].z, acc[0][t][3] + bias_fc[t].w);
                    *(uint2*)&outb[0 * 32 * XSTR + node * XSTR + colbase] = st;
                }
                {   // rate = softplus(acc1) + eps
                    float rv[4];
#pragma unroll
                    for (int r = 0; r < 4; ++r) {
                        const float v = acc[1][t][r];
                        rv[r] = fmaxf(v, 0.f) + __logf(1.f + __expf(-fabsf(v))) + EPSF;
                    }
                    uint2 st; st.x = pk2(rv[0], rv[1]); st.y = pk2(rv[2], rv[3]);
                    *(uint2*)&outb[1 * 32 * XSTR + node * XSTR + colbase] = st;
                }
                {   // gam = acc2 + brob
                    uint2 st;
                    st.x = pk2(acc[2][t][0] + bias_rob[t].x, acc[2][t][1] + bias_rob[t].y);
                    st.y = pk2(acc[2][t][2] + bias_rob[t].z, acc[2][t][3] + bias_rob[t].w);
                    *(uint2*)&outb[2 * 32 * XSTR + node * XSTR + colbase] = st;
                }
            }
        }
        __syncthreads();   // outb ready; xs reads done

        // ---- coalesced stores: wave writes 1KB contiguous runs
#pragma unroll
        for (int k = 0; k < 6; ++k) {
            const int w = k >> 1;
            const int rem = tid + (k & 1) * 256;        // 0..511
            const int node = rem >> 4, seg = rem & 15;  // seg: 16B chunk in row
            const uint4 v = *(const uint4*)&outb[w * 32 * XSTR + node * XSTR + seg * 8];
            ushort* dstw = (w == 0) ? h : (w == 1) ? rate : gam;
            *(uint4*)(dstw + (row0 + node) * DIM + seg * 8) = v;
        }

        // ---- stage prefetched next tile into xs
        if (hasnext) {
#pragma unroll
            for (int k = 0; k < 4; ++k) {
                const int i = tid + k * 256, r = i >> 5, c4 = i & 31;
                uint2 uu; uu.x = pk2(pf[k].x, pf[k].y); uu.y = pk2(pf[k].z, pf[k].w);
                *(uint2*)&xs[r * XSTR + c4 * 4] = uu;
            }
        }
        __syncthreads();   // xs ready; outb free
    }
}

// ---------------------------------------------------------------------------
// Fused gather + finalize + LayerNorm. One wave per FOUR rows; bucket rows
// loaded coalesced up-front, cols broadcast via shfl; gathers issued in
// fully-predicated 4x4 batches (16 independent loads in flight, no serial
// per-row tail loops). OOB slots clamp to row 0 and are masked in the add.
// ---------------------------------------------------------------------------
__global__ __launch_bounds__(256) void finalize_kernel(
    const ushort* __restrict__ h, const ushort* __restrict__ rate,
    const ushort* __restrict__ gam,
    const int* __restrict__ cur, const int* __restrict__ bucket,
    const int* __restrict__ degree,
    const float* __restrict__ ln_g, const float* __restrict__ ln_b,
    float* __restrict__ out)
{
    const int wave = threadIdx.x >> 6;
    const int lane = threadIdx.x & 63;
    const size_t r0 = (size_t)blockIdx.x * 16 + wave * 4;
    const unsigned* hu = (const unsigned*)h;

    // independent up-front loads (no chains)
    int nR[4]; float dgR[4]; int bvR[4];
    unsigned hvR[4], rvR[4], gvR[4];
#pragma unroll
    for (int q = 0; q < 4; ++q) {
        const size_t r = r0 + q;
        nR[q]  = cur[r];
        dgR[q] = (float)degree[r];
        bvR[q] = bucket[r * CAP + (lane & 31)];   // valid for idx < nR[q]
        hvR[q] = hu[r * 64 + lane];
        rvR[q] = ((const unsigned*)rate)[r * 64 + lane];
        gvR[q] = ((const unsigned*)gam)[r * 64 + lane];
    }
    const float2 lg = ((const float2*)ln_g)[lane];
    const float2 lb = ((const float2*)ln_b)[lane];

    float ax[4] = {0.f, 0.f, 0.f, 0.f}, ay[4] = {0.f, 0.f, 0.f, 0.f};
    const int mx = max(max(nR[0], nR[1]), max(nR[2], nR[3]));   // wave-uniform

    for (int j = 0; j < mx; j += 4) {
        unsigned v[4][4];
#pragma unroll
        for (int q = 0; q < 4; ++q)
#pragma unroll
            for (int p = 0; p < 4; ++p) {
                const int c = (j + p < nR[q]) ? __shfl(bvR[q], j + p, 64) : 0;
                v[q][p] = hu[(size_t)c * 64 + lane];
            }
#pragma unroll
        for (int q = 0; q < 4; ++q)
#pragma unroll
            for (int p = 0; p < 4; ++p) {
                const bool ok = (j + p < nR[q]);
                ax[q] += ok ? b2f((ushort)(v[q][p] & 0xffff)) : 0.f;
                ay[q] += ok ? b2f((ushort)(v[q][p] >> 16))    : 0.f;
            }
    }

    // ---- per-row math + LN + store
#pragma unroll
    for (int q = 0; q < 4; ++q) {
        const size_t row = r0 + q;
        const float cn = (float)nR[q];
        const float dg = dgR[q];

        const float h0 = b2f((ushort)(hvR[q] & 0xffff)), h1 = b2f((ushort)(hvR[q] >> 16));
        const float r0f = b2f((ushort)(rvR[q] & 0xffff)), r1f = b2f((ushort)(rvR[q] >> 16));
        const float g0 = b2f((ushort)(gvR[q] & 0xffff)), g1 = b2f((ushort)(gvR[q] >> 16));

        const float a0 = cn * h0 + ax[q];
        const float a1 = cn * h1 + ay[q];
        const float y0 = (r0f * a0 + g0) / (1.f + r0f * dg + EPSF);
        const float y1 = (r1f * a1 + g1) / (1.f + r1f * dg + EPSF);

        float s  = y0 + y1;
        float s2 = y0 * y0 + y1 * y1;
#pragma unroll
        for (int o = 32; o > 0; o >>= 1) {
            s  += __shfl_xor(s,  o, 64);
            s2 += __shfl_xor(s2, o, 64);
        }
        const float mean = s * (1.f / 128.f);
        const float var  = s2 * (1.f / 128.f) - mean * mean;
        const float inv  = rsqrtf(var + LN_EPSF);

        float2 o;
        o.x = (y0 - mean) * inv * lg.x + lb.x;
        o.y = (y1 - mean) * inv * lg.y + lb.y;
        ((float2*)(out + row * DIM))[lane] = o;
    }
}

// ---------------------------------------------------------------------------
extern "C" void kernel_launch(void* const* d_in, const int* in_sizes, int n_in,
                              void* d_out, int out_size, void* d_ws, size_t ws_size,
                              hipStream_t stream)
{
    const float* x      = (const float*)d_in[0];
    const int*   ei     = (const int*)  d_in[1];
    const int*   degree = (const int*)  d_in[2];
    const float* Wfc    = (const float*)d_in[3];
    const float* bfc    = (const float*)d_in[4];
    const float* Wrate  = (const float*)d_in[5];
    const float* Wrob   = (const float*)d_in[6];
    const float* brob   = (const float*)d_in[7];
    const float* ln_g   = (const float*)d_in[8];
    const float* ln_b   = (const float*)d_in[9];
    float* out = (float*)d_out;

    const int E = in_sizes[1] / 2;   // 800000
    const size_t NEL = (size_t)NN * DIM;

    ushort* h     = (ushort*)d_ws;
    ushort* rate  = h + NEL;
    ushort* gam   = rate + NEL;
    ushort* Bpack = gam + NEL;            // 6144*8 ushorts
    int*   cur    = (int*)(Bpack + 49152);
    int*   bucket = cur + NN;             // NN*CAP ints = 12.8 MB

    pack_kernel<<<PACK_GRID, 256, 0, stream>>>(Wfc, Wrate, Wrob, Bpack, cur);
    gemm3_mfma_kernel<<<GEMM_GRID, 256, 0, stream>>>(x, Bpack, bfc, brob,
                                                     h, rate, gam,
                                                     ei, cur, bucket, E);
    finalize_kernel<<<NN / 16, 256, 0, stream>>>(h, rate, gam, cur, bucket,
                                                 degree, ln_g, ln_b, out);
}